// Round 14
// baseline (72.833 us; speedup 1.0000x reference)
//
#include <hip/hip_runtime.h>
#include <cstddef>

#define BB 64
#define MM 5
#define NN 1000
#define DD 128
#define HH 8
#define KSZ 16
#define NT 8         // k2 tiles per (b,h), 125 n each
#define TN 125
#define NC3 8        // k3 chunks per b
#define CH3 125      // k3 chunk size
#define INV_SQRT_D 0.08838834764831845f

// k2 LDS tile regions (bytes)
#define K2_KOFF 0
#define K2_VOFF 8192
#define K2_NOFF 16384
#define K2_POFF 36864
#define K2_BUF  37376

typedef __attribute__((address_space(1))) const void gconst_t;
typedef __attribute__((address_space(3))) void lds_t;
#define GLD16(src, dst) __builtin_amdgcn_global_load_lds((gconst_t*)(src), (lds_t*)(dst), 16, 0, 0)
#define GLD4(src, dst)  __builtin_amdgcn_global_load_lds((gconst_t*)(src), (lds_t*)(dst), 4, 0, 0)
#define VMCNT0() asm volatile("s_waitcnt vmcnt(0)" ::: "memory")

__device__ __forceinline__ float tanh_fast(float x) {
  float e = __expf(2.f * x);
  return 1.f - 2.f / (e + 1.f);   // safe at +/-inf
}

// ---------------- k0: pure streaming read of all large inputs -> warms L3.
// Same access shape as the 6.3 TB/s copy ubench (grid-stride float4).
// Conditional never-taken sink write keeps the loads live.
__global__ __launch_bounds__(256) void k0_touch(
    const float4* __restrict__ gk, const float4* __restrict__ gv,
    const float4* __restrict__ nd, const float4* __restrict__ lk,
    float* __restrict__ sink)
{
  const size_t i0 = (size_t)blockIdx.x * 256 + threadIdx.x;
  const size_t stride = (size_t)gridDim.x * 256;
  float acc = 0.f;
  for (size_t i = i0; i < 2048000; i += stride) {   // gK: 8*64*1000*16 f32
    const float4 v = gk[i];
    acc += v.x + v.y + v.z + v.w;
  }
  for (size_t i = i0; i < 2048000; i += stride) {   // gV
    const float4 v = gv[i];
    acc += v.x + v.y + v.z + v.w;
  }
  for (size_t i = i0; i < 640000; i += stride) {    // ndf: 64*5*1000*8 f32
    const float4 v = nd[i];
    acc += v.x + v.y + v.z + v.w;
  }
  for (size_t i = i0; i < 2048000; i += stride) {   // lK: 64*1000*128 f32
    const float4 v = lk[i];
    acc += v.x + v.y + v.z + v.w;
  }
  if (acc == -1.23456789e33f) sink[blockIdx.x] = acc;   // never taken
}

// ---------------- k1: blocks [0,256): (b, d-quarter) query projection.
// Blocks [256,320): pack feasibility mask bits -> pmask[b][n].
__global__ __launch_bounds__(256) void k1_query(
    const float* __restrict__ fc, const float* __restrict__ pne,
    const float* __restrict__ vdf, const float* __restrict__ wpcv,
    const float* __restrict__ wpns, const int* __restrict__ mask,
    float* __restrict__ q_ws, float* __restrict__ qw_ws,
    unsigned int* __restrict__ pmask)
{
  const int t = threadIdx.x;
  if (blockIdx.x >= BB * 4) {          // mask-pack blocks
    const int b = blockIdx.x - BB * 4;
    const int* mb = mask + (size_t)(b * MM) * NN;
    for (int n = t; n < NN; n += 256) {
      unsigned int pm = 0;
#pragma unroll
      for (int m = 0; m < MM; ++m) pm |= (mb[m * NN + n] != 0 ? 1u : 0u) << m;
      pmask[b * NN + n] = pm;
    }
    return;
  }
  const int b = blockIdx.x >> 2;
  const int dq = blockIdx.x & 3;
  const int k = t & 15, gid = t >> 4;  // 16 groups of 16 lanes
  __shared__ float qsh[MM][32];

  float cvr[9];
  int curm = -1;
  for (int r = 0; r < 10; ++r) {       // r = m*2 + dhalf
    const int m = r >> 1;
    if (m != curm) {
      curm = m;
      const float* pner = pne + (size_t)(b * MM + m) * DD;
#pragma unroll
      for (int jp = 0; jp < 8; ++jp) cvr[jp] = pner[k + 16 * jp];
      cvr[8] = (k < 3) ? vdf[(b * MM + m) * 3 + k] : 0.f;
    }
    const int dl = (r & 1) * 16 + gid;
    const int d = dq * 32 + dl;
    const float* wrow = wpcv + d * 131;
    float p = 0.f;
#pragma unroll
    for (int jp = 0; jp < 8; ++jp) p = fmaf(cvr[jp], wrow[k + 16 * jp], p);
    if (k < 3) p = fmaf(cvr[8], wrow[128 + k], p);
    p += __shfl_xor(p, 1); p += __shfl_xor(p, 2);
    p += __shfl_xor(p, 4); p += __shfl_xor(p, 8);
    if (k == 0) {
      const float q = 0.25f * (p + fc[b * DD + d]);   // fold 1/sqrt(KS)
      qsh[m][dl] = q;
      q_ws[(size_t)(b * MM + m) * DD + d] = q;
    }
  }
  __syncthreads();
  if (t < 80) {
    const int hh = t / 40;             // 0/1 within this quarter
    const int r = t - hh * 40, m = r >> 3, f = r & 7;
    const int h = dq * 2 + hh;
    float acc = 0.f;
#pragma unroll
    for (int kk = 0; kk < KSZ; ++kk)
      acc = fmaf(qsh[m][hh * 16 + kk], wpns[(DD + h * KSZ + kk) * 8 + f], acc);
    qw_ws[(b * HH + h) * 40 + m * 8 + f] = acc;
  }
}

// ---------------- k2: per (b,h). Double-buffered global_load_lds streaming
// (R12 structure, unchanged — best measured config; now consumes L3-warm data).
__global__ __launch_bounds__(256, 2) void k2_attn(
    const float* __restrict__ ndf, const float* __restrict__ gV,
    const float* __restrict__ gK, const unsigned int* __restrict__ pmask,
    const float* __restrict__ q_ws, const float* __restrict__ qw_ws,
    float* __restrict__ part)
{
  const int bid = blockIdx.x;          // h*64 + b  -> xcd = b%8
  const int b = bid & 63;
  const int h = bid >> 6;
  const int t = threadIdx.x;
  const int w = t >> 6, lane = t & 63;
  const int k = t & 3, g = t >> 2;     // 64 groups of 4 lanes

  __shared__ __align__(16) char smem[2][K2_BUF];
  __shared__ float redh[4][MM][KSZ];
  __shared__ float redaf[4][MM][8];
  __shared__ float reds[4];

  const char* gkrow = (const char*)gK + (size_t)(h * BB + b) * (NN * 64);
  const char* gvrow = (const char*)gV + (size_t)(h * BB + b) * (NN * 64);
  const char* pmrow = (const char*)pmask + (size_t)b * (NN * 4);
  const char* ndrow0 = (const char*)ndf + (size_t)(b * MM) * (NN * 32);

  auto stage = [&](int tt, int bb) {
    char* base = smem[bb];
#pragma unroll
    for (int j = 0; j < 10; ++j) {
      const int seg = 4 * j + w;
      if (seg >= 38) continue;
      if (seg < 16) {                  // K (0..7) / V (8..15): 8000B/tile
        const int s = seg & 7;
        int off = tt * 8000 + s * 1024;
        if (off > NN * 64 - 1024) off = NN * 64 - 1024;   // row-local clamp
        const char* srow = (seg < 8) ? gkrow : gvrow;
        const int roff = (seg < 8) ? K2_KOFF : K2_VOFF;
        GLD16(srow + off + lane * 16, base + roff + (off - tt * 8000));
      } else if (seg < 36) {           // ndf: 5 rows x 4000B/tile
        const int rel = seg - 16, m = rel >> 2, q = rel & 3;
        int off = tt * 4000 + q * 1024;
        if (off > NN * 32 - 1024) off = NN * 32 - 1024;
        GLD16(ndrow0 + (size_t)m * (NN * 32) + off + lane * 16,
              base + K2_NOFF + m * 4096 + (off - tt * 4000));
      } else {                         // pmask: 500B/tile (waves 0,1)
        const int i4 = seg - 36;
        int off = tt * 500 + i4 * 256;
        if (off > NN * 4 - 256) off = NN * 4 - 256;
        GLD4(pmrow + off + lane * 4, base + K2_POFF + (off - tt * 500));
      }
    }
  };

  float4 qr[MM];
  float2 qw[MM];
#pragma unroll
  for (int m = 0; m < MM; ++m) {
    qr[m] = *(const float4*)(q_ws + (size_t)(b * MM + m) * DD + h * KSZ + 4 * k);
    qw[m] = *(const float2*)(qw_ws + (b * HH + h) * 40 + m * 8 + 2 * k);
  }

  float4 ha[MM] = {};
  float2 af[MM] = {};
  float ls = 0.f;

  stage(0, 0);
  VMCNT0();
  __builtin_amdgcn_s_barrier();

  for (int tt = 0; tt < NT; ++tt) {
    const int cur = tt & 1;
    if (tt < NT - 1) stage(tt + 1, cur ^ 1);
    const char* base = smem[cur];
#pragma unroll
    for (int i = 0; i < 2; ++i) {
      const int n = g + 64 * i;
      if (i == 0 || g < TN - 64) {
        const float4 kv = *(const float4*)(base + K2_KOFF + n * 64 + k * 16);
        const float4 vv = *(const float4*)(base + K2_VOFF + n * 64 + k * 16);
        const unsigned int pm = *(const unsigned int*)(base + K2_POFF + n * 4);
        float2 nd[MM];
#pragma unroll
        for (int m = 0; m < MM; ++m)
          nd[m] = *(const float2*)(base + K2_NOFF + m * 4096 + n * 32 + k * 8);
#pragma unroll
        for (int m = 0; m < MM; ++m) {
          float p = kv.x * qr[m].x + kv.y * qr[m].y
                  + kv.z * qr[m].z + kv.w * qr[m].w
                  + nd[m].x * qw[m].x + nd[m].y * qw[m].y;
          p += __shfl_xor(p, 1); p += __shfl_xor(p, 2);
          const float e = ((pm >> m) & 1u) ? __expf(p) : 0.f;
          ha[m].x = fmaf(e, vv.x, ha[m].x);
          ha[m].y = fmaf(e, vv.y, ha[m].y);
          ha[m].z = fmaf(e, vv.z, ha[m].z);
          ha[m].w = fmaf(e, vv.w, ha[m].w);
          af[m].x = fmaf(e, nd[m].x, af[m].x);
          af[m].y = fmaf(e, nd[m].y, af[m].y);
          ls += e;
        }
      }
    }
    VMCNT0();                          // next tile staged
    __builtin_amdgcn_s_barrier();      // all waves done with cur
  }

#pragma unroll
  for (int off = 4; off <= 32; off <<= 1) {
#pragma unroll
    for (int m = 0; m < MM; ++m) {
      ha[m].x += __shfl_xor(ha[m].x, off);
      ha[m].y += __shfl_xor(ha[m].y, off);
      ha[m].z += __shfl_xor(ha[m].z, off);
      ha[m].w += __shfl_xor(ha[m].w, off);
      af[m].x += __shfl_xor(af[m].x, off);
      af[m].y += __shfl_xor(af[m].y, off);
    }
    ls += __shfl_xor(ls, off);
  }
  if (lane < 4) {
#pragma unroll
    for (int m = 0; m < MM; ++m) {
      *(float4*)(&redh[w][m][4 * k]) = ha[m];
      *(float2*)(&redaf[w][m][2 * k]) = af[m];
    }
    if (k == 0) reds[w] = ls;
  }
  __syncthreads();
  float* P = part + (size_t)(b * HH + h) * 128;
  if (t < 80) {
    const int m = t >> 4, kk = t & 15;
    P[t] = redh[0][m][kk] + redh[1][m][kk] + redh[2][m][kk] + redh[3][m][kk];
  } else if (t < 120) {
    const int r = t - 80, m = r >> 3, f = r & 7;
    P[80 + r] = redaf[0][m][f] + redaf[1][m][f] + redaf[2][m][f] + redaf[3][m][f];
  } else if (t == 120) {
    P[120] = reds[0] + reds[1] + reds[2] + reds[3];
  }
}

// ---------------- k3: per (b,chunk). Fused combine + streaming logits.
__global__ __launch_bounds__(512) void k3_logits(
    const float* __restrict__ ndf, const float* __restrict__ lK,
    const unsigned int* __restrict__ pmask, const float* __restrict__ part,
    const float* __restrict__ wpns, const float* __restrict__ po,
    float* __restrict__ out, float* __restrict__ stats)
{
  const int b = blockIdx.x >> 3;
  const int c = blockIdx.x & 7;
  const int t = threadIdx.x;

  __shared__ float pos[DD][129];
  __shared__ float rgs[HH];
  __shared__ float afs[HH][MM][8];
  __shared__ float cs[MM][DD];
  __shared__ float fqs[MM][DD];
  __shared__ float fw[MM][8];
  __shared__ float wred[8];

  for (int i = t; i < DD * DD / 4; i += 512) {
    const float4 v = ((const float4*)po)[i];
    const int r = (i * 4) >> 7, cc = (i * 4) & 127;
    pos[r][cc] = v.x; pos[r][cc + 1] = v.y; pos[r][cc + 2] = v.z; pos[r][cc + 3] = v.w;
  }
  const float* pb = part + (size_t)b * HH * 128;
  if (t < HH) rgs[t] = 1.f / pb[t * 128 + 120];
  if (t < HH * MM * 8) {
    const int h = t / 40, r = t % 40;
    afs[h][r >> 3][r & 7] = pb[h * 128 + 80 + r];
  }
  __syncthreads();
  for (int idx = t; idx < MM * DD; idx += 512) {
    const int m = idx >> 7, d = idx & 127, h = d >> 4;
    const float a = pb[h * 128 + m * 16 + (d & 15)];
    float cf = 0.f;
#pragma unroll
    for (int f = 0; f < 8; ++f) cf = fmaf(wpns[d * 8 + f], afs[h][m][f], cf);
    cs[m][d] = (a + cf) * rgs[h];
  }
  __syncthreads();
  for (int idx = t; idx < MM * DD; idx += 512) {
    const int m = idx >> 7, d = idx & 127;
    float acc = 0.f;
#pragma unroll 8
    for (int j = 0; j < DD; ++j) acc = fmaf(cs[m][j], pos[d][j], acc);
    fqs[m][d] = acc * INV_SQRT_D;
  }
  __syncthreads();
  if (t < MM * 8) {
    const int m = t >> 3, f = t & 7;
    float acc = 0.f;
#pragma unroll 16
    for (int d = 0; d < DD; ++d) acc = fmaf(fqs[m][d], wpns[(2 * DD + d) * 8 + f], acc);
    fw[m][f] = acc;
  }
  __syncthreads();

  const int k = t & 15, gid = t >> 4;   // 32 groups of 16 lanes
  const int n0 = c * CH3;
  float4 fqr[MM][2];
  float fwr[MM];
#pragma unroll
  for (int m = 0; m < MM; ++m) {
    fqr[m][0] = *(const float4*)(&fqs[m][8 * k]);
    fqr[m][1] = *(const float4*)(&fqs[m][8 * k + 4]);
    fwr[m] = fw[m][k & 7];
  }
  float lsum = 0.f;

#pragma unroll
  for (int i = 0; i < 4; ++i) {
    const int nl = gid + 32 * i;
    const bool valid = (nl < CH3);          // group-uniform
    const int n = n0 + (valid ? nl : 0);
    const unsigned int pm = valid ? pmask[b * NN + n] : 0u;
    const float* lkr = lK + ((size_t)b * NN + n) * DD;
    const float4 l0 = *(const float4*)(lkr + 8 * k);
    const float4 l1 = *(const float4*)(lkr + 8 * k + 4);
    float ndv[MM];
#pragma unroll
    for (int m = 0; m < MM; ++m)
      ndv[m] = (k < 8) ? ndf[((size_t)(b * MM + m) * NN + n) * 8 + k] : 0.f;
#pragma unroll
    for (int m = 0; m < MM; ++m) {
      float p = l0.x * fqr[m][0].x + l0.y * fqr[m][0].y
              + l0.z * fqr[m][0].z + l0.w * fqr[m][0].w
              + l1.x * fqr[m][1].x + l1.y * fqr[m][1].y
              + l1.z * fqr[m][1].z + l1.w * fqr[m][1].w
              + ndv[m] * fwr[m];
      p += __shfl_xor(p, 1); p += __shfl_xor(p, 2);
      p += __shfl_xor(p, 4); p += __shfl_xor(p, 8);
      const float e = ((pm >> m) & 1u) ? __expf(tanh_fast(p) * 10.f) : 0.f;
      if (valid) {
        lsum += e;
        if (k == 0) out[(size_t)(b * MM + m) * NN + n] = e;
      }
    }
  }
  lsum += __shfl_xor(lsum, 16);
  lsum += __shfl_xor(lsum, 32);
  if ((t & 63) == 0) wred[t >> 6] = lsum;
  __syncthreads();
  if (t == 0) {
    float s = 0.f;
#pragma unroll
    for (int w2 = 0; w2 < 8; ++w2) s += wred[w2];
    stats[b * NC3 + c] = s;
  }
}

// ---------------- k4: per (b,m) scale row by 1/sum
__global__ __launch_bounds__(256) void k4_probs(
    const float* __restrict__ stats, float* __restrict__ out)
{
  const int bm = blockIdx.x;
  const int b = bm / MM;
  const int t = threadIdx.x;
  float s = 0.f;
#pragma unroll
  for (int c = 0; c < NC3; ++c) s += stats[b * NC3 + c];
  const float scale = 1.f / s;
  if (t < 250) {
    float4* p = (float4*)(out + (size_t)bm * NN);
    float4 v = p[t];
    v.x *= scale; v.y *= scale; v.z *= scale; v.w *= scale;
    p[t] = v;
  }
}

extern "C" void kernel_launch(void* const* d_in, const int* in_sizes, int n_in,
                              void* d_out, int out_size, void* d_ws, size_t ws_size,
                              hipStream_t stream) {
  // d_in[0] = node_embeddings: dead input, never read.
  const float* fc   = (const float*)d_in[1];
  const float* pne  = (const float*)d_in[2];
  const float* ndf  = (const float*)d_in[3];
  const float* vdf  = (const float*)d_in[4];
  const float* gV   = (const float*)d_in[5];
  const float* gK   = (const float*)d_in[6];
  const float* lK   = (const float*)d_in[7];
  const int*   mask = (const int*)d_in[8];
  const float* wpcv = (const float*)d_in[9];
  const float* wpns = (const float*)d_in[10];
  const float* po   = (const float*)d_in[11];

  float* q_ws  = (float*)d_ws;                        // 40960
  float* qw_ws = q_ws + BB * MM * DD;                 // 20480
  float* part  = qw_ws + BB * HH * 40;                // 64*8*128 = 65536
  float* stats = part + (size_t)BB * HH * 128;        // 512
  unsigned int* pmask = (unsigned int*)(stats + BB * NC3);  // 64000 u32
  float* sink  = (float*)(pmask + BB * NN);           // 2048 floats
  float* out   = (float*)d_out;

  k0_touch<<<2048, 256, 0, stream>>>((const float4*)gK, (const float4*)gV,
                                     (const float4*)ndf, (const float4*)lK, sink);
  k1_query<<<BB * 4 + BB, 256, 0, stream>>>(fc, pne, vdf, wpcv, wpns, mask,
                                            q_ws, qw_ws, pmask);
  k2_attn<<<HH * BB, 256, 0, stream>>>(ndf, gV, gK, pmask, q_ws, qw_ws, part);
  k3_logits<<<BB * NC3, 512, 0, stream>>>(ndf, lK, pmask, part, wpns, po, out, stats);
  k4_probs<<<BB * MM, 256, 0, stream>>>(stats, out);
}

// Round 15
// 56.276 us; speedup vs baseline: 1.2942x; 1.2942x over previous
//
#include <hip/hip_runtime.h>
#include <cstddef>

#define BB 64
#define MM 5
#define NN 1000
#define DD 128
#define HH 8
#define KSZ 16
#define NT 8         // k2 tiles per block (64 n each; block covers a 512-n half)
#define NC3 8        // k3 chunks per b
#define CH3 125      // k3 chunk size
#define INV_SQRT_D 0.08838834764831845f

// k2 LDS tile regions (bytes) within one buffer
#define K2_KOFF 0
#define K2_VOFF 4096
#define K2_NOFF 8192          // 5 x 2048
#define K2_POFF 18528         // 96B slack below for clamped pmask dest
#define K2_BUF  18816

typedef __attribute__((address_space(1))) const void gconst_t;
typedef __attribute__((address_space(3))) void lds_t;
#define GLD16(src, dst) __builtin_amdgcn_global_load_lds((gconst_t*)(src), (lds_t*)(dst), 16, 0, 0)
#define GLD4(src, dst)  __builtin_amdgcn_global_load_lds((gconst_t*)(src), (lds_t*)(dst), 4, 0, 0)
#define VMCNT0() asm volatile("s_waitcnt vmcnt(0)" ::: "memory")

__device__ __forceinline__ float tanh_fast(float x) {
  float e = __expf(2.f * x);
  return 1.f - 2.f / (e + 1.f);   // safe at +/-inf
}

// ---------------- k1: blocks [0,256): (b, d-quarter) query projection.
// Blocks [256,320): pack feasibility mask bits -> pmask[b][n].
__global__ __launch_bounds__(256) void k1_query(
    const float* __restrict__ fc, const float* __restrict__ pne,
    const float* __restrict__ vdf, const float* __restrict__ wpcv,
    const float* __restrict__ wpns, const int* __restrict__ mask,
    float* __restrict__ q_ws, float* __restrict__ qw_ws,
    unsigned int* __restrict__ pmask)
{
  const int t = threadIdx.x;
  if (blockIdx.x >= BB * 4) {          // mask-pack blocks
    const int b = blockIdx.x - BB * 4;
    const int* mb = mask + (size_t)(b * MM) * NN;
    for (int n = t; n < NN; n += 256) {
      unsigned int pm = 0;
#pragma unroll
      for (int m = 0; m < MM; ++m) pm |= (mb[m * NN + n] != 0 ? 1u : 0u) << m;
      pmask[b * NN + n] = pm;
    }
    return;
  }
  const int b = blockIdx.x >> 2;
  const int dq = blockIdx.x & 3;
  const int k = t & 15, gid = t >> 4;  // 16 groups of 16 lanes
  __shared__ float qsh[MM][32];

  float cvr[9];
  int curm = -1;
  for (int r = 0; r < 10; ++r) {       // r = m*2 + dhalf
    const int m = r >> 1;
    if (m != curm) {
      curm = m;
      const float* pner = pne + (size_t)(b * MM + m) * DD;
#pragma unroll
      for (int jp = 0; jp < 8; ++jp) cvr[jp] = pner[k + 16 * jp];
      cvr[8] = (k < 3) ? vdf[(b * MM + m) * 3 + k] : 0.f;
    }
    const int dl = (r & 1) * 16 + gid;
    const int d = dq * 32 + dl;
    const float* wrow = wpcv + d * 131;
    float p = 0.f;
#pragma unroll
    for (int jp = 0; jp < 8; ++jp) p = fmaf(cvr[jp], wrow[k + 16 * jp], p);
    if (k < 3) p = fmaf(cvr[8], wrow[128 + k], p);
    p += __shfl_xor(p, 1); p += __shfl_xor(p, 2);
    p += __shfl_xor(p, 4); p += __shfl_xor(p, 8);
    if (k == 0) {
      const float q = 0.25f * (p + fc[b * DD + d]);   // fold 1/sqrt(KS)
      qsh[m][dl] = q;
      q_ws[(size_t)(b * MM + m) * DD + d] = q;
    }
  }
  __syncthreads();
  if (t < 80) {
    const int hh = t / 40;             // 0/1 within this quarter
    const int r = t - hh * 40, m = r >> 3, f = r & 7;
    const int h = dq * 2 + hh;
    float acc = 0.f;
#pragma unroll
    for (int kk = 0; kk < KSZ; ++kk)
      acc = fmaf(qsh[m][hh * 16 + kk], wpns[(DD + h * KSZ + kk) * 8 + f], acc);
    qw_ws[(b * HH + h) * 40 + m * 8 + f] = acc;
  }
}

// ---------------- k2: per (b,h,half). R12 double-buffered global_load_lds
// pipeline, but 1024 blocks with 18.8KB buffers -> 4 blocks/CU co-resident
// (2x the outstanding loads of R12, to pull harder during the poison-drain
// window). Each block: 8 tiles of 64 n over its 512-n half (half1: 488 n).
// Record per (b,h,half): [m*16+kk]=sum e*V ; [80+m*8+f]=sum e*ndf ; [120]=sum e.
__global__ __launch_bounds__(256, 4) void k2_attn(
    const float* __restrict__ ndf, const float* __restrict__ gV,
    const float* __restrict__ gK, const unsigned int* __restrict__ pmask,
    const float* __restrict__ q_ws, const float* __restrict__ qw_ws,
    float* __restrict__ part)
{
  const int bid = blockIdx.x;          // (h*2+half)*64 + b  -> xcd = b%8
  const int b = bid & 63;
  const int hp = bid >> 6;             // h*2 + half
  const int h = hp >> 1;
  const int half = hp & 1;
  const int t = threadIdx.x;
  const int w = t >> 6, lane = t & 63;
  const int k = t & 3, g = t >> 2;     // 64 groups of 4 lanes; 1 n per tile
  const int n0 = half * 512;
  const int nlen = half ? (NN - 512) : 512;   // 488 or 512

  __shared__ __align__(16) char smem[2][K2_BUF];
  __shared__ float redh[4][MM][KSZ];
  __shared__ float redaf[4][MM][8];
  __shared__ float reds[4];

  const char* gkrow = (const char*)gK + (size_t)(h * BB + b) * (NN * 64);
  const char* gvrow = (const char*)gV + (size_t)(h * BB + b) * (NN * 64);
  const char* pmrow = (const char*)pmask + (size_t)b * (NN * 4);
  const char* ndrow0 = (const char*)ndf + (size_t)(b * MM) * (NN * 32);

  // stage tile tt into buffer bb (19 segs over 4 waves; wave w: segs 4j+w)
  auto stage = [&](int tt, int bb) {
    char* base = smem[bb];
    const int tb = n0 + tt * 64;       // tile base node
#pragma unroll
    for (int j = 0; j < 5; ++j) {
      const int seg = 4 * j + w;
      if (seg >= 19) continue;
      if (seg < 8) {                   // K (0..3) / V (4..7): 4096B/tile
        const int s = seg & 3;
        const int tilb = tb * 64;
        int off = tilb + s * 1024;
        if (off > NN * 64 - 1024) off = NN * 64 - 1024;   // row-local clamp
        const char* srow = (seg < 4) ? gkrow : gvrow;
        const int roff = (seg < 4) ? K2_KOFF : K2_VOFF;
        GLD16(srow + off + lane * 16, base + roff + (off - tilb));
      } else if (seg < 18) {           // ndf: 5 rows x 2048B/tile
        const int rel = seg - 8, m = rel >> 1, q = rel & 1;
        const int tilb = tb * 32;
        int off = tilb + q * 1024;
        if (off > NN * 32 - 1024) off = NN * 32 - 1024;
        GLD16(ndrow0 + (size_t)m * (NN * 32) + off + lane * 16,
              base + K2_NOFF + m * 2048 + (off - tilb));
      } else {                         // pmask: 256B/tile (1 seg, wave 2)
        const int tilb = tb * 4;
        int off = tilb;
        if (off > NN * 4 - 256) off = NN * 4 - 256;   // dest >= POFF-96
        GLD4(pmrow + off + lane * 4, base + K2_POFF + (off - tilb));
      }
    }
  };

  float4 qr[MM];
  float2 qw[MM];
#pragma unroll
  for (int m = 0; m < MM; ++m) {
    qr[m] = *(const float4*)(q_ws + (size_t)(b * MM + m) * DD + h * KSZ + 4 * k);
    qw[m] = *(const float2*)(qw_ws + (b * HH + h) * 40 + m * 8 + 2 * k);
  }

  float4 ha[MM] = {};
  float2 af[MM] = {};
  float ls = 0.f;

  stage(0, 0);
  VMCNT0();
  __builtin_amdgcn_s_barrier();

  for (int tt = 0; tt < NT; ++tt) {
    const int cur = tt & 1;
    if (tt < NT - 1) stage(tt + 1, cur ^ 1);
    const char* base = smem[cur];
    const int nv = nlen - tt * 64;     // valid n this tile (64, or 40 last)
    if (g < nv) {
      const int n = g;
      const float4 kv = *(const float4*)(base + K2_KOFF + n * 64 + k * 16);
      const float4 vv = *(const float4*)(base + K2_VOFF + n * 64 + k * 16);
      const unsigned int pm = *(const unsigned int*)(base + K2_POFF + n * 4);
      float2 nd[MM];
#pragma unroll
      for (int m = 0; m < MM; ++m)
        nd[m] = *(const float2*)(base + K2_NOFF + m * 2048 + n * 32 + k * 8);
#pragma unroll
      for (int m = 0; m < MM; ++m) {
        float p = kv.x * qr[m].x + kv.y * qr[m].y
                + kv.z * qr[m].z + kv.w * qr[m].w
                + nd[m].x * qw[m].x + nd[m].y * qw[m].y;
        p += __shfl_xor(p, 1); p += __shfl_xor(p, 2);
        const float e = ((pm >> m) & 1u) ? __expf(p) : 0.f;
        ha[m].x = fmaf(e, vv.x, ha[m].x);
        ha[m].y = fmaf(e, vv.y, ha[m].y);
        ha[m].z = fmaf(e, vv.z, ha[m].z);
        ha[m].w = fmaf(e, vv.w, ha[m].w);
        af[m].x = fmaf(e, nd[m].x, af[m].x);
        af[m].y = fmaf(e, nd[m].y, af[m].y);
        ls += e;
      }
    }
    VMCNT0();                          // next tile staged
    __builtin_amdgcn_s_barrier();      // all waves done with cur
  }

  // wave butterfly across the 16 groups (k-slot preserved by xor>=4)
#pragma unroll
  for (int off = 4; off <= 32; off <<= 1) {
#pragma unroll
    for (int m = 0; m < MM; ++m) {
      ha[m].x += __shfl_xor(ha[m].x, off);
      ha[m].y += __shfl_xor(ha[m].y, off);
      ha[m].z += __shfl_xor(ha[m].z, off);
      ha[m].w += __shfl_xor(ha[m].w, off);
      af[m].x += __shfl_xor(af[m].x, off);
      af[m].y += __shfl_xor(af[m].y, off);
    }
    ls += __shfl_xor(ls, off);
  }
  if (lane < 4) {
#pragma unroll
    for (int m = 0; m < MM; ++m) {
      *(float4*)(&redh[w][m][4 * k]) = ha[m];
      *(float2*)(&redaf[w][m][2 * k]) = af[m];
    }
    if (k == 0) reds[w] = ls;
  }
  __syncthreads();
  float* P = part + (size_t)((b * HH + h) * 2 + half) * 128;
  if (t < 80) {
    const int m = t >> 4, kk = t & 15;
    P[t] = redh[0][m][kk] + redh[1][m][kk] + redh[2][m][kk] + redh[3][m][kk];
  } else if (t < 120) {
    const int r = t - 80, m = r >> 3, f = r & 7;
    P[80 + r] = redaf[0][m][f] + redaf[1][m][f] + redaf[2][m][f] + redaf[3][m][f];
  } else if (t == 120) {
    P[120] = reds[0] + reds[1] + reds[2] + reds[3];
  }
}

// ---------------- k3: per (b,chunk). Fused: combine half-records -> conc ->
// fq,fw then streaming logits -> e-values. part: 2 records per (b,h).
__global__ __launch_bounds__(512) void k3_logits(
    const float* __restrict__ ndf, const float* __restrict__ lK,
    const unsigned int* __restrict__ pmask, const float* __restrict__ part,
    const float* __restrict__ wpns, const float* __restrict__ po,
    float* __restrict__ out, float* __restrict__ stats)
{
  const int b = blockIdx.x >> 3;
  const int c = blockIdx.x & 7;
  const int t = threadIdx.x;

  __shared__ float pos[DD][129];   // stride 129: conflict-free column reads
  __shared__ float rgs[HH];
  __shared__ float afs[HH][MM][8];
  __shared__ float cs[MM][DD];
  __shared__ float fqs[MM][DD];
  __shared__ float fw[MM][8];
  __shared__ float wred[8];

  for (int i = t; i < DD * DD / 4; i += 512) {
    const float4 v = ((const float4*)po)[i];
    const int r = (i * 4) >> 7, cc = (i * 4) & 127;
    pos[r][cc] = v.x; pos[r][cc + 1] = v.y; pos[r][cc + 2] = v.z; pos[r][cc + 3] = v.w;
  }
  const float* pb = part + (size_t)b * HH * 2 * 128;
  if (t < HH) rgs[t] = 1.f / (pb[(t * 2) * 128 + 120] + pb[(t * 2 + 1) * 128 + 120]);
  if (t < HH * MM * 8) {
    const int h = t / 40, r = t % 40;
    afs[h][r >> 3][r & 7] = pb[(h * 2) * 128 + 80 + r] + pb[(h * 2 + 1) * 128 + 80 + r];
  }
  __syncthreads();
  for (int idx = t; idx < MM * DD; idx += 512) {
    const int m = idx >> 7, d = idx & 127, h = d >> 4;
    const float a = pb[(h * 2) * 128 + m * 16 + (d & 15)]
                  + pb[(h * 2 + 1) * 128 + m * 16 + (d & 15)];
    float cf = 0.f;
#pragma unroll
    for (int f = 0; f < 8; ++f) cf = fmaf(wpns[d * 8 + f], afs[h][m][f], cf);
    cs[m][d] = (a + cf) * rgs[h];
  }
  __syncthreads();
  for (int idx = t; idx < MM * DD; idx += 512) {
    const int m = idx >> 7, d = idx & 127;
    float acc = 0.f;
#pragma unroll 8
    for (int j = 0; j < DD; ++j) acc = fmaf(cs[m][j], pos[d][j], acc);
    fqs[m][d] = acc * INV_SQRT_D;
  }
  __syncthreads();
  if (t < MM * 8) {
    const int m = t >> 3, f = t & 7;
    float acc = 0.f;
#pragma unroll 16
    for (int d = 0; d < DD; ++d) acc = fmaf(fqs[m][d], wpns[(2 * DD + d) * 8 + f], acc);
    fw[m][f] = acc;
  }
  __syncthreads();

  // ---- streaming logits (16-lane shfl-dot, direct exp)
  const int k = t & 15, gid = t >> 4;   // 32 groups of 16 lanes
  const int n0 = c * CH3;
  float4 fqr[MM][2];
  float fwr[MM];
#pragma unroll
  for (int m = 0; m < MM; ++m) {
    fqr[m][0] = *(const float4*)(&fqs[m][8 * k]);
    fqr[m][1] = *(const float4*)(&fqs[m][8 * k + 4]);
    fwr[m] = fw[m][k & 7];
  }
  float lsum = 0.f;

#pragma unroll
  for (int i = 0; i < 4; ++i) {
    const int nl = gid + 32 * i;
    const bool valid = (nl < CH3);          // group-uniform
    const int n = n0 + (valid ? nl : 0);
    const unsigned int pm = valid ? pmask[b * NN + n] : 0u;
    const float* lkr = lK + ((size_t)b * NN + n) * DD;
    const float4 l0 = *(const float4*)(lkr + 8 * k);
    const float4 l1 = *(const float4*)(lkr + 8 * k + 4);
    float ndv[MM];
#pragma unroll
    for (int m = 0; m < MM; ++m)
      ndv[m] = (k < 8) ? ndf[((size_t)(b * MM + m) * NN + n) * 8 + k] : 0.f;
#pragma unroll
    for (int m = 0; m < MM; ++m) {
      float p = l0.x * fqr[m][0].x + l0.y * fqr[m][0].y
              + l0.z * fqr[m][0].z + l0.w * fqr[m][0].w
              + l1.x * fqr[m][1].x + l1.y * fqr[m][1].y
              + l1.z * fqr[m][1].z + l1.w * fqr[m][1].w
              + ndv[m] * fwr[m];
      p += __shfl_xor(p, 1); p += __shfl_xor(p, 2);
      p += __shfl_xor(p, 4); p += __shfl_xor(p, 8);
      const float e = ((pm >> m) & 1u) ? __expf(tanh_fast(p) * 10.f) : 0.f;
      if (valid) {
        lsum += e;
        if (k == 0) out[(size_t)(b * MM + m) * NN + n] = e;
      }
    }
  }
  lsum += __shfl_xor(lsum, 16);
  lsum += __shfl_xor(lsum, 32);
  if ((t & 63) == 0) wred[t >> 6] = lsum;
  __syncthreads();
  if (t == 0) {
    float s = 0.f;
#pragma unroll
    for (int w2 = 0; w2 < 8; ++w2) s += wred[w2];
    stats[b * NC3 + c] = s;
  }
}

// ---------------- k4: per (b,m) scale row by 1/sum
__global__ __launch_bounds__(256) void k4_probs(
    const float* __restrict__ stats, float* __restrict__ out)
{
  const int bm = blockIdx.x;
  const int b = bm / MM;
  const int t = threadIdx.x;
  float s = 0.f;
#pragma unroll
  for (int c = 0; c < NC3; ++c) s += stats[b * NC3 + c];
  const float scale = 1.f / s;
  if (t < 250) {
    float4* p = (float4*)(out + (size_t)bm * NN);
    float4 v = p[t];
    v.x *= scale; v.y *= scale; v.z *= scale; v.w *= scale;
    p[t] = v;
  }
}

extern "C" void kernel_launch(void* const* d_in, const int* in_sizes, int n_in,
                              void* d_out, int out_size, void* d_ws, size_t ws_size,
                              hipStream_t stream) {
  // d_in[0] = node_embeddings: dead input, never read.
  const float* fc   = (const float*)d_in[1];
  const float* pne  = (const float*)d_in[2];
  const float* ndf  = (const float*)d_in[3];
  const float* vdf  = (const float*)d_in[4];
  const float* gV   = (const float*)d_in[5];
  const float* gK   = (const float*)d_in[6];
  const float* lK   = (const float*)d_in[7];
  const int*   mask = (const int*)d_in[8];
  const float* wpcv = (const float*)d_in[9];
  const float* wpns = (const float*)d_in[10];
  const float* po   = (const float*)d_in[11];

  float* q_ws  = (float*)d_ws;                        // 40960
  float* qw_ws = q_ws + BB * MM * DD;                 // 20480
  float* part  = qw_ws + BB * HH * 40;                // 64*8*2*128 = 131072
  float* stats = part + (size_t)BB * HH * 2 * 128;    // 512
  unsigned int* pmask = (unsigned int*)(stats + BB * NC3);  // 64000 u32
  float* out   = (float*)d_out;

  k1_query<<<BB * 4 + BB, 256, 0, stream>>>(fc, pne, vdf, wpcv, wpns, mask,
                                            q_ws, qw_ws, pmask);
  k2_attn<<<HH * 2 * BB, 256, 0, stream>>>(ndf, gV, gK, pmask, q_ws, qw_ws, part);
  k3_logits<<<BB * NC3, 512, 0, stream>>>(ndf, lK, pmask, part, wpns, po, out, stats);
  k4_probs<<<BB * MM, 256, 0, stream>>>(stats, out);
}